// Round 10
// baseline (608.432 us; speedup 1.0000x reference)
//
#include <hip/hip_runtime.h>

// SpikingSiameseNetwork forward, MI355X/gfx950.
// prep(3-way bf16 weight split) -> GEMM1 -> LIF1 -> GEMM2 -> tail1+tail2.
// Numerics: activations exactly {0,1}; weights split into 3 bf16 parts summed
// in fp32 MFMA accumulator => fp32-exact (absmax 0.0 through R6).
// R6: gload_lds + 3 blk/CU -> 139us gemm1, but all pipes <25%: latency-bound.
// R7 "2.5-phase" design FAILED correctness: stageA_lds j-stride staged A rows
//     64-95 into LDS rows 32-63 (64*KSRC*2 B = 64 rows, not 32). R8 fixes the
//     stride to 32*KSRC*2 (R8/R9 benches never ran: broker timeouts; resubmit):
//  - B double-buffered, prefetch issued at TOP of compute(c) -> drain at the
//    region-end syncthreads overlaps compute; parity: s0 reads buf[kb&1],
//    s1 buf[kb+1&1], s2 buf[kb&1].
//  - A stored bf16 in LDS; gemm1 packs fp32->bf16 in regs pipelined one kb
//    ahead (A-LDS only read during s0 -> overwrite at s1/s2 barrier-safe);
//    gemm2 stages A via gload_lds issued at s1.
//  - A-fragments held in registers across the 3 weight splits (LDS reads /3).
//  - tail split: tail1 one-segment-per-block (2048 blocks), tail2 mean.

typedef short bf16x8 __attribute__((ext_vector_type(8)));
typedef float f32x4 __attribute__((ext_vector_type(4)));

#define RBIG 51200  // BS(2048) * T(25)

__device__ __forceinline__ void glds16(const void* g, void* l) {
    __builtin_amdgcn_global_load_lds((const __attribute__((address_space(1))) void*)g,
                                     (__attribute__((address_space(3))) void*)l, 16, 0, 0);
}
__device__ __forceinline__ unsigned int pk2(float lo, float hi) {
    return (__float_as_uint(hi) & 0xFFFF0000u) | (__float_as_uint(lo) >> 16);
}

// ---------------- prep: split fp32 weights into 3 bf16 parts --------------
__global__ void prep_w(const float* __restrict__ Wa1, const float* __restrict__ Wv1,
                       const float* __restrict__ Wa2, const float* __restrict__ Wv2,
                       unsigned short* __restrict__ W1s, unsigned short* __restrict__ W2s) {
    int idx = blockIdx.x * 256 + threadIdx.x;  // total 327680 exactly
    float w;
    unsigned short* dst;
    int K, k;
    if (idx < 262144) {
        int p = idx >> 17, rem = idx & 131071;
        int n = rem >> 9; k = rem & 511; K = 512;
        const float* src = p ? Wv1 : Wa1;
        w = src[(size_t)n * 512 + k];
        dst = W1s + (size_t)p * 256 * 1536 + (size_t)n * 1536;
    } else {
        int j = idx - 262144;
        int p = j >> 15, rem = j & 32767;
        int n = rem >> 8; k = rem & 255; K = 256;
        const float* src = p ? Wv2 : Wa2;
        w = src[(size_t)n * 256 + k];
        dst = W2s + (size_t)p * 128 * 768 + (size_t)n * 768;
    }
    unsigned int u  = __float_as_uint(w);
    unsigned int hi = u & 0xFFFF0000u;
    float r1 = w - __uint_as_float(hi);
    unsigned int mi = __float_as_uint(r1) & 0xFFFF0000u;
    float r2 = r1 - __uint_as_float(mi);
    dst[k]         = (unsigned short)(hi >> 16);
    dst[K + k]     = (unsigned short)(mi >> 16);
    dst[2 * K + k] = (unsigned short)(__float_as_uint(r2) >> 16);
}

// ---------------- GEMM: C[51200 x NT] = A * W'^T ---------------------------
template <int KSRC, int NT, int BM, int BN, int MINW, bool AF32>
__global__ __launch_bounds__(256, MINW) void gemmT(
    const void* __restrict__ A0, const void* __restrict__ A1,
    const unsigned short* __restrict__ Ws, float* __restrict__ C) {
    constexpr int KE   = 3 * KSRC;
    constexpr int NKB  = KSRC / 64;
    constexpr int MFR  = BM / 2 / 16;
    constexpr int NFR  = BN / 2 / 16;
    constexpr int NBY  = NT / BN;
    constexpr int NBG  = BN / 32;   // B 16B-granule gloads per thread
    constexpr int NAGL = BM / 32;   // A granule gloads per thread (!AF32)

    __shared__ __align__(1024) unsigned short Al[BM * 64];
    __shared__ __align__(1024) unsigned short Bl[2][BN * 64];

    const int tid  = threadIdx.x, lane = tid & 63, wave = tid >> 6;
    const int wm   = wave >> 1, wn = wave & 1;

    // XCD-aware bijective swizzle (nwg % 8 == 0); low bits -> (by,bz)
    const int nwg = gridDim.x;
    const int orig = blockIdx.x;
    const int lid = (orig & 7) * (nwg >> 3) + (orig >> 3);
    const int by = lid % NBY;
    const int t0 = lid / NBY;
    const int bz = t0 & 1;
    const int bx = t0 >> 1;
    const size_t row0 = (size_t)bx * BM;

    const char* Abase = (const char*)(bz ? A1 : A0) + row0 * KSRC * (AF32 ? 4 : 2);
    const char* Bbase = (const char*)Ws + ((size_t)bz * NT + (size_t)by * BN) * KE * 2;

    // ---- B staging: gload_lds, pre-swizzled source, linear dest ----
    const int rowB0 = tid >> 3, slB = tid & 7;
    const size_t offB0 = (size_t)rowB0 * KE * 2 + (size_t)((slB ^ (rowB0 & 7)) << 4);
    const int dst0 = wave * 1024;
    auto stageB = [&](int kb, int sp, int buf) {
        const char* s = Bbase + ((size_t)sp * KSRC + (size_t)kb * 64) * 2 + offB0;
        char* d = (char*)Bl[buf] + dst0;
#pragma unroll
        for (int j = 0; j < NBG; ++j)
            glds16(s + (size_t)j * (32 * KE * 2), d + j * 4096);  // +32 rows/j
    };

    // ---- A staging ----
    // AF32: global fp32 -> regs -> pack bf16 -> swizzled ds_write (half-row
    //       per thread; two temporal halves hv=0,1 of 4 float4 each).
    const int rowA = tid >> 1, halfA = tid & 1;
    auto loadAh = [&](int kb, int hv, float4 (&a)[4]) {
        const float* p = (const float*)Abase + (size_t)rowA * KSRC + kb * 64 + halfA * 32 + hv * 16;
#pragma unroll
        for (int q = 0; q < 4; ++q) a[q] = *(const float4*)(p + q * 4);
    };
    auto packwA = [&](int hv, float4 (&a)[4]) {
        uint4 u0, u1;
        u0.x = pk2(a[0].x, a[0].y); u0.y = pk2(a[0].z, a[0].w);
        u0.z = pk2(a[1].x, a[1].y); u0.w = pk2(a[1].z, a[1].w);
        u1.x = pk2(a[2].x, a[2].y); u1.y = pk2(a[2].z, a[2].w);
        u1.z = pk2(a[3].x, a[3].y); u1.w = pk2(a[3].z, a[3].w);
        int g0 = halfA * 4 + hv * 2;
        *(uint4*)&Al[rowA * 64 + ((g0 ^ (rowA & 7)) << 3)]       = u0;
        *(uint4*)&Al[rowA * 64 + (((g0 + 1) ^ (rowA & 7)) << 3)] = u1;
    };
    // !AF32: direct gload_lds (source already bf16)
    const int rowAS = tid >> 3, slAS = tid & 7;
    const size_t offA0 = (size_t)rowAS * KSRC * 2 + (size_t)((slAS ^ (rowAS & 7)) << 4);
    auto stageA_lds = [&](int kb) {
        const char* s = Abase + (size_t)kb * 64 * 2 + offA0;
        char* d = (char*)Al + dst0;
#pragma unroll
        for (int j = 0; j < NAGL; ++j)
            glds16(s + (size_t)j * (32 * KSRC * 2), d + j * 4096);  // +32 rows/j (R7 bug: was 64)
    };

    f32x4 acc[MFR][NFR];
    f32x4 zz = {0.f, 0.f, 0.f, 0.f};
#pragma unroll
    for (int i = 0; i < MFR; ++i)
#pragma unroll
        for (int j = 0; j < NFR; ++j) acc[i][j] = zz;

    const int ko0 = (lane >> 4) << 3;
    const int rfr = lane & 15;
    bf16x8 af[MFR][2];

    auto loadAfrags = [&]() {
#pragma unroll
        for (int mi = 0; mi < MFR; ++mi)
#pragma unroll
            for (int ks = 0; ks < 2; ++ks) {
                int r = wm * (BM / 2) + mi * 16 + rfr;
                af[mi][ks] = *(const bf16x8*)&Al[(r * 64 + ks * 32 + ko0) ^ ((r & 7) << 3)];
            }
    };
    auto comp = [&](int buf) {
#pragma unroll
        for (int ks = 0; ks < 2; ++ks) {
            const int kbase = ks * 32 + ko0;
            bf16x8 bb[NFR];
#pragma unroll
            for (int ni = 0; ni < NFR; ++ni) {
                int n = wn * (BN / 2) + ni * 16 + rfr;
                bb[ni] = *(const bf16x8*)&Bl[buf][(n * 64 + kbase) ^ ((n & 7) << 3)];
            }
#pragma unroll
            for (int mi = 0; mi < MFR; ++mi)
#pragma unroll
                for (int ni = 0; ni < NFR; ++ni)
                    acc[mi][ni] = __builtin_amdgcn_mfma_f32_16x16x32_bf16(
                        af[mi][ks], bb[ni], acc[mi][ni], 0, 0, 0);
        }
    };

    // ---- prologue: A(0) + B(0,0) ----
    float4 a0h[4], a1h[4];
    if constexpr (AF32) {
        loadAh(0, 0, a0h); loadAh(0, 1, a1h);
        packwA(0, a0h);    packwA(1, a1h);
    } else {
        stageA_lds(0);
    }
    stageB(0, 0, 0);
    __syncthreads();

#pragma unroll 1
    for (int kb = 0; kb < NKB; ++kb) {
        const bool more = (kb + 1 < NKB);
        const int pb = kb & 1, qb = pb ^ 1;
        // ---- s = 0 : reads Bl[pb] ----
        loadAfrags();                       // A(kb) frags -> regs (held all kb)
        stageB(kb, 1, qb);                  // prefetch, flies under compute
        if constexpr (AF32) { if (more) loadAh(kb + 1, 0, a0h); }
        comp(pb);
        __syncthreads();
        // ---- s = 1 : reads Bl[qb]; A-LDS overwrite now safe ----
        stageB(kb, 2, pb);
        if constexpr (AF32) {
            if (more) { packwA(0, a0h); loadAh(kb + 1, 1, a1h); }
        } else {
            if (more) stageA_lds(kb + 1);
        }
        comp(qb);
        __syncthreads();
        // ---- s = 2 : reads Bl[pb] ----
        if (more) stageB(kb + 1, 0, qb);
        if constexpr (AF32) { if (more) packwA(1, a1h); }
        comp(pb);
        __syncthreads();
    }

    // epilogue: C/D layout col=lane&15, row=(lane>>4)*4+reg (m89-verified)
    float* Cp = C + (size_t)bz * RBIG * NT;
    int r4 = ((lane >> 4) << 2), cl = lane & 15;
#pragma unroll
    for (int mi = 0; mi < MFR; ++mi)
#pragma unroll
        for (int ni = 0; ni < NFR; ++ni) {
            size_t col = (size_t)by * BN + wn * (BN / 2) + ni * 16 + cl;
#pragma unroll
            for (int j = 0; j < 4; ++j) {
                size_t row = row0 + wm * (BM / 2) + mi * 16 + r4 + j;
                Cp[row * NT + col] = acc[mi][ni][j];
            }
        }
}

// ---------------- LIF layer 1: scan over t, emit bf16 spikes ---------------
__global__ void lif1_k(const float* __restrict__ cur, const float* __restrict__ ba1,
                       const float* __restrict__ bv1, unsigned int* __restrict__ spk) {
    int r = blockIdx.x, p = blockIdx.y, d = threadIdx.x;  // 128 threads
    const float* c0 = cur + ((size_t)p * RBIG + (size_t)r * 25) * 256 + 2 * d;
    const float* bias = p ? bv1 : ba1;
    float b0 = bias[2 * d], b1 = bias[2 * d + 1];
    float2 cv[25];
#pragma unroll
    for (int t = 0; t < 25; ++t) cv[t] = *(const float2*)(c0 + (size_t)t * 256);
    unsigned int* sp = spk + ((size_t)p * RBIG + (size_t)r * 25) * 128 + d;
    float m0 = 0.f, m1 = 0.f;
#pragma unroll
    for (int t = 0; t < 25; ++t) {
        float r0 = (m0 > 1.f) ? 1.f : 0.f;  // reset from PREVIOUS mem
        float r1 = (m1 > 1.f) ? 1.f : 0.f;
        m0 = 0.9f * m0 + (cv[t].x + b0) - r0;
        m1 = 0.9f * m1 + (cv[t].y + b1) - r1;
        unsigned int w = (m0 > 1.f ? 0x3F80u : 0u) | (m1 > 1.f ? 0x3F800000u : 0u);
        sp[(size_t)t * 128] = w;
    }
}

// ------- tail1: LIF2 scan + L2-normalize, one segment per block ------------
__global__ void tail1_k(const float* __restrict__ cur2, const float* __restrict__ ba2,
                        const float* __restrict__ bv2, float* __restrict__ normd) {
    int r = blockIdx.x, d = threadIdx.x;  // 2048 blocks, 256 threads
    int p = d >> 7, e = d & 127;
    const float* bias = p ? bv2 : ba2;
    float bo = bias[e];
    const float* c0 = cur2 + ((size_t)p * RBIG + (size_t)r * 25) * 128 + e;
    float cv[25];
#pragma unroll
    for (int t = 0; t < 25; ++t) cv[t] = c0[(size_t)t * 128];
    float m = 0.f;
#pragma unroll
    for (int t = 0; t < 25; ++t) {
        float rs = (m > 1.f) ? 1.f : 0.f;
        m = 0.9f * m + (cv[t] + bo) - rs;
    }
    float v = (m > 1.f) ? 1.f : 0.f;
    __shared__ float part[4];
    float sq = v;  // v in {0,1}: v*v == v; sum order-exact
#pragma unroll
    for (int off = 32; off > 0; off >>= 1) sq += __shfl_down(sq, off);
    if ((d & 63) == 0) part[d >> 6] = sq;
    __syncthreads();
    float nrm = sqrtf(part[0] + part[1] + part[2] + part[3]);
    normd[(size_t)r * 256 + d] = v / fmaxf(nrm, 1e-12f);
}

// ------- tail2: mean over the 8 segments of each batch ---------------------
__global__ void tail2_k(const float* __restrict__ normd, float* __restrict__ out) {
    int b = blockIdx.x, d = threadIdx.x;  // 256 blocks, 256 threads
    float acc = 0.f;
#pragma unroll
    for (int s = 0; s < 8; ++s) acc += normd[((size_t)(b * 8 + s)) * 256 + d];
    out[(size_t)b * 256 + d] = acc * 0.125f;
}

extern "C" void kernel_launch(void* const* d_in, const int* in_sizes, int n_in,
                              void* d_out, int out_size, void* d_ws, size_t ws_size,
                              hipStream_t stream) {
    const float* a_seq = (const float*)d_in[0];
    const float* v_seq = (const float*)d_in[1];
    const float* W_a1  = (const float*)d_in[2];
    const float* b_a1  = (const float*)d_in[3];
    const float* W_a2  = (const float*)d_in[4];
    const float* b_a2  = (const float*)d_in[5];
    const float* W_v1  = (const float*)d_in[6];
    const float* b_v1  = (const float*)d_in[7];
    const float* W_v2  = (const float*)d_in[8];
    const float* b_v2  = (const float*)d_in[9];

    char* ws = (char*)d_ws;  // ~159.3 MB used
    unsigned short* W1s  = (unsigned short*)(ws);              // 1,572,864 B
    unsigned short* W2s  = (unsigned short*)(ws + 1572864);    //   393,216 B
    unsigned short* spk1 = (unsigned short*)(ws + 1966080);    // 52,428,800 B
    float*          curb = (float*)(ws + 54394880);            // 104,857,600 B
    float*          normd= (float*)(ws + 1966080);             // reuse spk1 area (2 MB; spk1 dead after gemm2)
    float*          out  = (float*)d_out;

    prep_w<<<1280, 256, 0, stream>>>(W_a1, W_v1, W_a2, W_v2, W1s, W2s);

    // layer 1: cur1[p][51200][256]; BM=128 BN=128 (by=2), 1600 blocks,
    // LDS 48KB (A bf16 16 + B dbuf 32) -> 3 blk/CU
    gemmT<512, 256, 128, 128, 3, true><<<1600, 256, 0, stream>>>(
        a_seq, v_seq, W1s, curb);
    lif1_k<<<dim3(2048, 2), 128, 0, stream>>>(curb, b_a1, b_v1, (unsigned int*)spk1);

    // layer 2: cur2[p][51200][128]; BM=64 BN=128, 1600 blocks,
    // LDS 40KB (A 8 + B dbuf 32) -> 4 blk/CU
    gemmT<256, 128, 64, 128, 4, false><<<1600, 256, 0, stream>>>(
        spk1, spk1 + (size_t)RBIG * 256, W2s, curb);

    tail1_k<<<2048, 256, 0, stream>>>(curb, b_a2, b_v2, normd);
    tail2_k<<<256, 256, 0, stream>>>(normd, out);
}